// Round 12
// baseline (823.278 us; speedup 1.0000x reference)
//
#include <hip/hip_runtime.h>
#include <hip/hip_bf16.h>

#define F 128

typedef __attribute__((ext_vector_type(8))) short short8;    // 8 bf16 = 4 VGPRs
typedef __attribute__((ext_vector_type(4))) float floatx4;   // MFMA C/D

__device__ __forceinline__ float bf_lo(unsigned u) { return __uint_as_float(u << 16); }
__device__ __forceinline__ float bf_hi(unsigned u) { return __uint_as_float(u & 0xffff0000u); }

// fp32 -> bf16 bits, round-to-nearest-even
__device__ __forceinline__ unsigned short f2bf(float x) {
  unsigned u = __float_as_uint(x);
  u += 0x7fffu + ((u >> 16) & 1u);
  return (unsigned short)(u >> 16);
}
__device__ __forceinline__ unsigned pack2(float a, float b) {
  return (unsigned)f2bf(a) | ((unsigned)f2bf(b) << 16);
}
__device__ __forceinline__ void add8(float* a, uint4 u) {
  a[0] += bf_lo(u.x); a[1] += bf_hi(u.x);
  a[2] += bf_lo(u.y); a[3] += bf_hi(u.y);
  a[4] += bf_lo(u.z); a[5] += bf_hi(u.z);
  a[6] += bf_lo(u.w); a[7] += bf_hi(u.w);
}

// -------- merged: dst histogram + x->bf16 convert + both weight transposes --------
__global__ __launch_bounds__(256) void k_pre(const int* __restrict__ dst, int* __restrict__ A,
                                             int E, int cb,
                                             const float* __restrict__ x,
                                             const float* __restrict__ Wl0,
                                             const float* __restrict__ Wr0,
                                             const float* __restrict__ Wl1,
                                             const float* __restrict__ Wr1,
                                             unsigned short* __restrict__ xb,
                                             unsigned short* __restrict__ WcatT0,
                                             unsigned short* __restrict__ WcatT1, int n4) {
  if (blockIdx.x < cb) {
    int e = blockIdx.x * 256 + threadIdx.x;
    if (e < E) atomicAdd(&A[dst[e]], 1);
    return;
  }
  int i = (blockIdx.x - cb) * 256 + threadIdx.x;
  if (i < n4) {
    float4 v = ((const float4*)x)[i];
    ((ushort4*)xb)[i] = make_ushort4(f2bf(v.x), f2bf(v.y), f2bf(v.z), f2bf(v.w));
  } else {
    int j = i - n4;
    if (j < 2 * 256 * F) {
      int layer = j >> 15;
      int jj = j & 32767;
      int k = jj >> 7, n = jj & (F - 1);
      const float* Wl = layer ? Wl1 : Wl0;
      const float* Wr = layer ? Wr1 : Wr0;
      unsigned short* WT = layer ? WcatT1 : WcatT0;
      float v = (k < F) ? Wl[k * F + n] : Wr[(k - F) * F + n];
      WT[(size_t)n * 256 + k] = f2bf(v);
    }
  }
}

// -------- single-kernel exclusive scan: 49 co-resident blocks, ticket + flag --------
// (merges R11's scanA + scanC; 49 blocks <= 256 CUs so spin is deadlock-free)
__global__ __launch_bounds__(1024) void k_scan(int* __restrict__ A, int* __restrict__ bsum,
                                               int* __restrict__ bases, int* __restrict__ ctl,
                                               int n, int nb) {
  __shared__ int wtot[16];
  __shared__ int lastS, sbase;
  int t = threadIdx.x, l = t & 63, w = t >> 6;
  int i = blockIdx.x * 1024 + t;
  int v = (i < n) ? A[i] : 0;
  int acc = v;
#pragma unroll
  for (int off = 1; off < 64; off <<= 1) {
    int u = __shfl_up(acc, off);
    if (l >= off) acc += u;
  }
  if (l == 63) wtot[w] = acc;
  __syncthreads();
  int woff = 0, total = 0;
#pragma unroll
  for (int ww = 0; ww < 16; ++ww) {
    total += wtot[ww];
    if (ww < w) woff += wtot[ww];
  }
  int local = woff + (acc - v);  // block-local exclusive prefix
  if (t == 0) {
    __hip_atomic_store(&bsum[blockIdx.x], total, __ATOMIC_RELEASE, __HIP_MEMORY_SCOPE_AGENT);
    int tk = __hip_atomic_fetch_add(&ctl[0], 1, __ATOMIC_ACQ_REL, __HIP_MEMORY_SCOPE_AGENT);
    lastS = (tk == nb - 1);
  }
  __syncthreads();
  if (lastS) {
    if (t < 64) {
      int bv = (t < nb) ? __hip_atomic_load(&bsum[t], __ATOMIC_ACQUIRE, __HIP_MEMORY_SCOPE_AGENT) : 0;
      int a2 = bv;
#pragma unroll
      for (int off = 1; off < 64; off <<= 1) {
        int u = __shfl_up(a2, off);
        if (t >= off) a2 += u;
      }
      if (t < nb)
        __hip_atomic_store(&bases[t], a2 - bv, __ATOMIC_RELAXED, __HIP_MEMORY_SCOPE_AGENT);
    }
    __syncthreads();
    if (t == 0) {
      __threadfence();
      __hip_atomic_store(&ctl[1], 1, __ATOMIC_RELEASE, __HIP_MEMORY_SCOPE_AGENT);
    }
  }
  if (t == 0) {
    while (__hip_atomic_load(&ctl[1], __ATOMIC_ACQUIRE, __HIP_MEMORY_SCOPE_AGENT) == 0) {}
    sbase = __hip_atomic_load(&bases[blockIdx.x], __ATOMIC_RELAXED, __HIP_MEMORY_SCOPE_AGENT);
  }
  __syncthreads();
  if (i < n) A[i] = local + sbase;
}

// -------- CSR fill: A becomes row-end (inclusive) --------
__global__ __launch_bounds__(256) void k_fill(const int* __restrict__ srcT,
                                              const int* __restrict__ dst,
                                              int* __restrict__ A, int* __restrict__ adj, int E) {
  int e = blockIdx.x * 256 + threadIdx.x;
  if (e >= E) return;
  int s = srcT[e], d = dst[e];
  int slot = atomicAdd(&A[d], 1);
  adj[slot] = s;
}

// -------- mean aggregation v3: TWO dst rows per wave. DO NOT fuse into gemm (R10). --------
__global__ __launch_bounds__(256) void k_gather(const unsigned short* __restrict__ xin,
                                                const int* __restrict__ A,
                                                const int* __restrict__ adj,
                                                unsigned short* __restrict__ aggb, int N) {
  int base = blockIdx.x * 8 + ((threadIdx.x >> 6) << 1);
  int l = threadIdx.x & 63;
  int grp = l >> 4, ln = l & 15;
  const uint4* xrows = (const uint4*)xin;

  int d0 = base, d1 = base + 1;
  bool v0 = d0 < N, v1 = d1 < N;
  int e00 = 0, e01 = 0, e10 = 0, e11 = 0;
  if (v0) { e00 = (d0 == 0) ? 0 : A[d0 - 1]; e01 = A[d0]; }
  if (v1) { e10 = A[d1 - 1]; e11 = A[d1]; }  // d1 >= 1 always
  int deg0 = e01 - e00, deg1 = e11 - e10;
  int ids0 = 0, ids1 = 0;
  if (v0 && deg0 > 0) ids0 = adj[min(e00 + l, e01 - 1)];
  if (v1 && deg1 > 0) ids1 = adj[min(e10 + l, e11 - 1)];
  int m0 = (v0 && deg0 > 0) ? min(deg0, 64) : 0;
  int m1 = (v1 && deg1 > 0) ? min(deg1, 64) : 0;
  int mm = max(m0, m1);

  float acc0[8] = {0.f, 0.f, 0.f, 0.f, 0.f, 0.f, 0.f, 0.f};
  float acc1[8] = {0.f, 0.f, 0.f, 0.f, 0.f, 0.f, 0.f, 0.f};
  for (int j0 = 0; j0 < mm; j0 += 4) {
    int jj = j0 + grp;
    int s0 = __shfl(ids0, jj);
    int s1 = __shfl(ids1, jj);
    if (jj < m0) { uint4 u = xrows[(size_t)s0 * 16 + ln]; add8(acc0, u); }
    if (jj < m1) { uint4 u = xrows[(size_t)s1 * 16 + ln]; add8(acc1, u); }
  }
  for (int e = e00 + 64 + grp; e < e01; e += 4) {  // rare: deg > 64
    int s = adj[e];
    uint4 u = xrows[(size_t)s * 16 + ln];
    add8(acc0, u);
  }
  for (int e = e10 + 64 + grp; e < e11; e += 4) {
    int s = adj[e];
    uint4 u = xrows[(size_t)s * 16 + ln];
    add8(acc1, u);
  }
#pragma unroll
  for (int k2 = 0; k2 < 8; ++k2) {
    acc0[k2] += __shfl_xor(acc0[k2], 16);
    acc0[k2] += __shfl_xor(acc0[k2], 32);
    acc1[k2] += __shfl_xor(acc1[k2], 16);
    acc1[k2] += __shfl_xor(acc1[k2], 32);
  }
  if (grp == 0) {
    if (v0) {
      float inv = 1.0f / fmaxf((float)deg0, 1.0f);
      uint4 o = make_uint4(pack2(acc0[0] * inv, acc0[1] * inv), pack2(acc0[2] * inv, acc0[3] * inv),
                           pack2(acc0[4] * inv, acc0[5] * inv), pack2(acc0[6] * inv, acc0[7] * inv));
      ((uint4*)aggb)[(size_t)d0 * 16 + ln] = o;
    }
    if (v1) {
      float inv = 1.0f / fmaxf((float)deg1, 1.0f);
      uint4 o = make_uint4(pack2(acc1[0] * inv, acc1[1] * inv), pack2(acc1[2] * inv, acc1[3] * inv),
                           pack2(acc1[4] * inv, acc1[5] * inv), pack2(acc1[6] * inv, acc1[7] * inv));
      ((uint4*)aggb)[(size_t)d1 * 16 + ln] = o;
    }
  }
}

// -------- MFMA gemm + ticketed BN-stats finalize (bnstats dispatch folded in) --------
// 4 waves/block; wave w owns cols [32w, 32w+32). B fragments in registers.
// Epilogue: shfl-reduced partials -> pbuf (agent-scope stores), ticket; last
// block reduces 782x256 (coalesced) and writes scale/shift. No same-address
// atomic chains (R3-R5 lesson); stats ticket pattern proven in R9/R10.
__global__ __launch_bounds__(256, 2) void k_gemm(
    const unsigned short* __restrict__ aggb, const unsigned short* __restrict__ xb,
    const unsigned short* __restrict__ WcatT, const float* __restrict__ bias,
    unsigned short* __restrict__ hb, float* __restrict__ pbuf, int* __restrict__ ticket,
    const float* __restrict__ g, const float* __restrict__ be,
    float* __restrict__ scale, float* __restrict__ shift, float invN, int N) {
  __shared__ float red[256];
  __shared__ int lastS;
  const int w = threadIdx.x >> 6;
  const int l = threadIdx.x & 63;
  const int lm = l & 15;   // tile row (A) / tile col (B, C/D)
  const int lq = l >> 4;   // quad
  const int cbase = 32 * w;

  short8 bfrag[2][8];
#pragma unroll
  for (int c = 0; c < 2; ++c) {
    int col = cbase + 16 * c + lm;
    const unsigned short* wp = WcatT + (size_t)col * 256 + lq * 8;
#pragma unroll
    for (int s = 0; s < 8; ++s) bfrag[c][s] = *(const short8*)(wp + 32 * s);
  }
  float bcol0 = bias[cbase + lm];
  float bcol1 = bias[cbase + 16 + lm];
  float bsum0 = 0.f, bsum1 = 0.f, bsq0 = 0.f, bsq1 = 0.f;

  int r0 = blockIdx.x * 64;  // grid == nRowBlocks
  floatx4 acc[4][2] = {};
#pragma unroll
  for (int t = 0; t < 4; ++t) {
    int r = r0 + 16 * t + lm;  // pad rows exist (poison = tiny bf16); stores/stats guarded
    const unsigned short* arow = aggb + (size_t)r * F + lq * 8;
    const unsigned short* xrow = xb + (size_t)r * F + lq * 8;
    short8 af[8];
#pragma unroll
    for (int s = 0; s < 4; ++s) {
      af[s] = *(const short8*)(arow + 32 * s);
      af[s + 4] = *(const short8*)(xrow + 32 * s);
    }
#pragma unroll
    for (int s = 0; s < 8; ++s) {
      acc[t][0] = __builtin_amdgcn_mfma_f32_16x16x32_bf16(af[s], bfrag[0][s], acc[t][0], 0, 0, 0);
      acc[t][1] = __builtin_amdgcn_mfma_f32_16x16x32_bf16(af[s], bfrag[1][s], acc[t][1], 0, 0, 0);
    }
  }
#pragma unroll
  for (int t = 0; t < 4; ++t) {
#pragma unroll
    for (int c = 0; c < 2; ++c) {
      int col = cbase + 16 * c + lm;
      float bc = c ? bcol1 : bcol0;
#pragma unroll
      for (int gg = 0; gg < 4; ++gg) {
        int row = r0 + 16 * t + lq * 4 + gg;
        if (row < N) {
          float v = acc[t][c][gg] + bc;
          hb[(size_t)row * F + col] = f2bf(v);
          if (c) { bsum1 += v; bsq1 += v * v; }
          else   { bsum0 += v; bsq0 += v * v; }
        }
      }
    }
  }
  bsum0 += __shfl_xor(bsum0, 16); bsum0 += __shfl_xor(bsum0, 32);
  bsq0  += __shfl_xor(bsq0, 16);  bsq0  += __shfl_xor(bsq0, 32);
  bsum1 += __shfl_xor(bsum1, 16); bsum1 += __shfl_xor(bsum1, 32);
  bsq1  += __shfl_xor(bsq1, 16);  bsq1  += __shfl_xor(bsq1, 32);
  if (lq == 0) {
    float* pb = pbuf + (size_t)blockIdx.x * 256;
    __hip_atomic_store(&pb[cbase + lm], bsum0, __ATOMIC_RELAXED, __HIP_MEMORY_SCOPE_AGENT);
    __hip_atomic_store(&pb[128 + cbase + lm], bsq0, __ATOMIC_RELAXED, __HIP_MEMORY_SCOPE_AGENT);
    __hip_atomic_store(&pb[cbase + 16 + lm], bsum1, __ATOMIC_RELAXED, __HIP_MEMORY_SCOPE_AGENT);
    __hip_atomic_store(&pb[128 + cbase + 16 + lm], bsq1, __ATOMIC_RELAXED, __HIP_MEMORY_SCOPE_AGENT);
  }
  __threadfence();
  __syncthreads();
  if (threadIdx.x == 0) {
    int tk = __hip_atomic_fetch_add(ticket, 1, __ATOMIC_ACQ_REL, __HIP_MEMORY_SCOPE_AGENT);
    lastS = (tk == (int)gridDim.x - 1);
  }
  __syncthreads();
  if (lastS) {
    __threadfence();
    float s = 0.f;
    int nb = gridDim.x;
    for (int b = 0; b < nb; ++b)
      s += __hip_atomic_load(&pbuf[(size_t)b * 256 + threadIdx.x], __ATOMIC_RELAXED,
                             __HIP_MEMORY_SCOPE_AGENT);
    red[threadIdx.x] = s;
    __syncthreads();
    if (threadIdx.x < 128) {
      float mu = red[threadIdx.x] * invN;
      float var = fmaxf(red[threadIdx.x + 128] * invN - mu * mu, 0.0f);
      float sc = g[threadIdx.x] * rsqrtf(var + 1e-5f);
      scale[threadIdx.x] = sc;
      shift[threadIdx.x] = be[threadIdx.x] - mu * sc;
    }
  }
}

// -------- BN apply + ReLU: bf16 h -> bf16 dst (8 elems/thread) --------
__global__ __launch_bounds__(256) void k_bnrelu(const unsigned short* __restrict__ h,
                                                unsigned short* __restrict__ dst,
                                                const float* __restrict__ scale,
                                                const float* __restrict__ shift, int n8) {
  int i = blockIdx.x * 256 + threadIdx.x;
  if (i >= n8) return;
  uint4 u = ((const uint4*)h)[i];
  int g = i & 15;
  float4 sc0 = ((const float4*)scale)[2 * g];
  float4 sc1 = ((const float4*)scale)[2 * g + 1];
  float4 sh0 = ((const float4*)shift)[2 * g];
  float4 sh1 = ((const float4*)shift)[2 * g + 1];
  unsigned o0 = pack2(fmaxf(fmaf(bf_lo(u.x), sc0.x, sh0.x), 0.f),
                      fmaxf(fmaf(bf_hi(u.x), sc0.y, sh0.y), 0.f));
  unsigned o1 = pack2(fmaxf(fmaf(bf_lo(u.y), sc0.z, sh0.z), 0.f),
                      fmaxf(fmaf(bf_hi(u.y), sc0.w, sh0.w), 0.f));
  unsigned o2 = pack2(fmaxf(fmaf(bf_lo(u.z), sc1.x, sh1.x), 0.f),
                      fmaxf(fmaf(bf_hi(u.z), sc1.y, sh1.y), 0.f));
  unsigned o3 = pack2(fmaxf(fmaf(bf_lo(u.w), sc1.z, sh1.z), 0.f),
                      fmaxf(fmaf(bf_hi(u.w), sc1.w, sh1.w), 0.f));
  ((uint4*)dst)[i] = make_uint4(o0, o1, o2, o3);
}

// -------- fused BN1 + ReLU + final linear 128->2: hb -> out --------
__global__ __launch_bounds__(256) void k_bnout(const unsigned short* __restrict__ hb,
                                               const float* __restrict__ scale,
                                               const float* __restrict__ shift,
                                               const float* __restrict__ Wout,
                                               const float* __restrict__ bout,
                                               float* __restrict__ out, int N) {
  __shared__ float W0s[F], W1s[F];
  int t = threadIdx.x;
  if (t < F) {
    W0s[t] = Wout[2 * t];
    W1s[t] = Wout[2 * t + 1];
  }
  __syncthreads();
  int r = blockIdx.x * 16 + (t >> 4);
  int ln = t & 15;
  if (r >= N) return;
  uint4 u = ((const uint4*)(hb + (size_t)r * F))[ln];
  float4 sc0 = ((const float4*)scale)[2 * ln];
  float4 sc1 = ((const float4*)scale)[2 * ln + 1];
  float4 sh0 = ((const float4*)shift)[2 * ln];
  float4 sh1 = ((const float4*)shift)[2 * ln + 1];
  float v[8];
  v[0] = fmaxf(fmaf(bf_lo(u.x), sc0.x, sh0.x), 0.f);
  v[1] = fmaxf(fmaf(bf_hi(u.x), sc0.y, sh0.y), 0.f);
  v[2] = fmaxf(fmaf(bf_lo(u.y), sc0.z, sh0.z), 0.f);
  v[3] = fmaxf(fmaf(bf_hi(u.y), sc0.w, sh0.w), 0.f);
  v[4] = fmaxf(fmaf(bf_lo(u.z), sc1.x, sh1.x), 0.f);
  v[5] = fmaxf(fmaf(bf_hi(u.z), sc1.y, sh1.y), 0.f);
  v[6] = fmaxf(fmaf(bf_lo(u.w), sc1.z, sh1.z), 0.f);
  v[7] = fmaxf(fmaf(bf_hi(u.w), sc1.w, sh1.w), 0.f);
  float a0 = 0.f, a1 = 0.f;
#pragma unroll
  for (int j = 0; j < 8; ++j) {
    a0 += v[j] * W0s[8 * ln + j];
    a1 += v[j] * W1s[8 * ln + j];
  }
#pragma unroll
  for (int off = 1; off < 16; off <<= 1) {
    a0 += __shfl_xor(a0, off);
    a1 += __shfl_xor(a1, off);
  }
  if (ln == 0) {
    out[2 * r]     = a0 + bout[0];
    out[2 * r + 1] = a1 + bout[1];
  }
}

extern "C" void kernel_launch(void* const* d_in, const int* in_sizes, int n_in,
                              void* d_out, int out_size, void* d_ws, size_t ws_size,
                              hipStream_t stream) {
  const float* x   = (const float*)d_in[0];
  const int*   eix = (const int*)d_in[1];
  const float* Wl0 = (const float*)d_in[2];
  const float* Wr0 = (const float*)d_in[3];
  const float* b0  = (const float*)d_in[4];
  const float* g0  = (const float*)d_in[5];
  const float* be0 = (const float*)d_in[6];
  const float* Wl1 = (const float*)d_in[7];
  const float* Wr1 = (const float*)d_in[8];
  const float* b1  = (const float*)d_in[9];
  const float* g1  = (const float*)d_in[10];
  const float* be1 = (const float*)d_in[11];
  const float* Wo  = (const float*)d_in[12];
  const float* bo  = (const float*)d_in[13];

  int N = in_sizes[0] / F;     // 50000
  int E = in_sizes[1] / 2;     // 600000
  const int* src  = eix;
  const int* dstv = eix + E;

  int nRowBlocks = (N + 63) / 64;         // 782
  size_t Npad = (size_t)nRowBlocks * 64;  // 50048
  int nScanB = (N + 1023) / 1024;         // 49

  // ws layout: aggb | xb | hb (bf16 Npad*F) | WcatT0 | WcatT1 | scale | shift |
  //            A[N] | bsum[64] | bases[64] | ctl[4] | adj[E] | pbuf
  unsigned short* aggb   = (unsigned short*)d_ws;
  unsigned short* xb     = aggb + Npad * F;
  unsigned short* hb     = xb + Npad * F;
  unsigned short* WcatT0 = hb + Npad * F;
  unsigned short* WcatT1 = WcatT0 + 256 * F;
  float* scale = (float*)(WcatT1 + 256 * F);
  float* shift = scale + F;
  int*   A     = (int*)(shift + F);
  int*   bsum  = A + N;
  int*   bases = bsum + 64;
  int*   ctl   = bases + 64;            // [0]=scan ticket [1]=scan flag [2]=gemm0 [3]=gemm1
  int*   adj   = ctl + 4;
  float* pbuf  = (float*)(adj + E);     // [nRowBlocks][256]

  // zero A + bsum + bases + ctl in one contiguous memset
  hipMemsetAsync(A, 0, (size_t)(N + 132) * sizeof(int), stream);

  int n4 = N * F / 4, n8 = N * F / 8;
  int cb = (E + 255) / 256;

  // ---- merged: histogram + x conversion + weight transposes ----
  k_pre<<<cb + (n4 + 2 * 256 * F + 255) / 256, 256, 0, stream>>>(
      dstv, A, E, cb, x, Wl0, Wr0, Wl1, Wr1, xb, WcatT0, WcatT1, n4);

  // ---- CSR scan (single kernel) + fill ----
  k_scan<<<nScanB, 1024, 0, stream>>>(A, bsum, bases, ctl, N, nScanB);
  k_fill<<<(E + 255) / 256, 256, 0, stream>>>(src, dstv, A, adj, E);

  // ---- layer 0 ----
  k_gather<<<(N + 7) / 8, 256, 0, stream>>>(xb, A, adj, aggb, N);
  k_gemm<<<nRowBlocks, 256, 0, stream>>>(aggb, xb, WcatT0, b0, hb, pbuf, ctl + 2,
                                         g0, be0, scale, shift, 1.0f / N, N);
  k_bnrelu<<<(n8 + 255) / 256, 256, 0, stream>>>(hb, xb, scale, shift, n8);  // -> xb

  // ---- layer 1 ----
  k_gather<<<(N + 7) / 8, 256, 0, stream>>>(xb, A, adj, aggb, N);
  k_gemm<<<nRowBlocks, 256, 0, stream>>>(aggb, xb, WcatT1, b1, hb, pbuf, ctl + 3,
                                         g1, be1, scale, shift, 1.0f / N, N);

  // ---- fused BN1 + ReLU + output head ----
  k_bnout<<<(N + 15) / 16, 256, 0, stream>>>(hb, scale, shift, Wo, bo, (float*)d_out, N);
}

// Round 13
// 337.453 us; speedup vs baseline: 2.4397x; 2.4397x over previous
//
#include <hip/hip_runtime.h>
#include <hip/hip_bf16.h>

#define F 128

typedef __attribute__((ext_vector_type(8))) short short8;    // 8 bf16 = 4 VGPRs
typedef __attribute__((ext_vector_type(4))) float floatx4;   // MFMA C/D

__device__ __forceinline__ float bf_lo(unsigned u) { return __uint_as_float(u << 16); }
__device__ __forceinline__ float bf_hi(unsigned u) { return __uint_as_float(u & 0xffff0000u); }

// fp32 -> bf16 bits, round-to-nearest-even
__device__ __forceinline__ unsigned short f2bf(float x) {
  unsigned u = __float_as_uint(x);
  u += 0x7fffu + ((u >> 16) & 1u);
  return (unsigned short)(u >> 16);
}
__device__ __forceinline__ unsigned pack2(float a, float b) {
  return (unsigned)f2bf(a) | ((unsigned)f2bf(b) << 16);
}
__device__ __forceinline__ void add8(float* a, uint4 u) {
  a[0] += bf_lo(u.x); a[1] += bf_hi(u.x);
  a[2] += bf_lo(u.y); a[3] += bf_hi(u.y);
  a[4] += bf_lo(u.z); a[5] += bf_hi(u.z);
  a[6] += bf_lo(u.w); a[7] += bf_hi(u.w);
}

// -------- merged: dst histogram + x->bf16 convert + both weight transposes --------
__global__ __launch_bounds__(256) void k_pre(const int* __restrict__ dst, int* __restrict__ A,
                                             int E, int cb,
                                             const float* __restrict__ x,
                                             const float* __restrict__ Wl0,
                                             const float* __restrict__ Wr0,
                                             const float* __restrict__ Wl1,
                                             const float* __restrict__ Wr1,
                                             unsigned short* __restrict__ xb,
                                             unsigned short* __restrict__ WcatT0,
                                             unsigned short* __restrict__ WcatT1, int n4) {
  if (blockIdx.x < cb) {
    int e = blockIdx.x * 256 + threadIdx.x;
    if (e < E) atomicAdd(&A[dst[e]], 1);
    return;
  }
  int i = (blockIdx.x - cb) * 256 + threadIdx.x;
  if (i < n4) {
    float4 v = ((const float4*)x)[i];
    ((ushort4*)xb)[i] = make_ushort4(f2bf(v.x), f2bf(v.y), f2bf(v.z), f2bf(v.w));
  } else {
    int j = i - n4;
    if (j < 2 * 256 * F) {
      int layer = j >> 15;
      int jj = j & 32767;
      int k = jj >> 7, n = jj & (F - 1);
      const float* Wl = layer ? Wl1 : Wl0;
      const float* Wr = layer ? Wr1 : Wr0;
      unsigned short* WT = layer ? WcatT1 : WcatT0;
      float v = (k < F) ? Wl[k * F + n] : Wr[(k - F) * F + n];
      WT[(size_t)n * 256 + k] = f2bf(v);
    }
  }
}

// -------- single-kernel exclusive scan: 49 co-resident blocks, ticket + flag --------
// (proven neutral-or-better in R12; the R12 regression was the gemm epilogue, not this)
__global__ __launch_bounds__(1024) void k_scan(int* __restrict__ A, int* __restrict__ bsum,
                                               int* __restrict__ bases, int* __restrict__ ctl,
                                               int n, int nb) {
  __shared__ int wtot[16];
  __shared__ int lastS, sbase;
  int t = threadIdx.x, l = t & 63, w = t >> 6;
  int i = blockIdx.x * 1024 + t;
  int v = (i < n) ? A[i] : 0;
  int acc = v;
#pragma unroll
  for (int off = 1; off < 64; off <<= 1) {
    int u = __shfl_up(acc, off);
    if (l >= off) acc += u;
  }
  if (l == 63) wtot[w] = acc;
  __syncthreads();
  int woff = 0, total = 0;
#pragma unroll
  for (int ww = 0; ww < 16; ++ww) {
    total += wtot[ww];
    if (ww < w) woff += wtot[ww];
  }
  int local = woff + (acc - v);  // block-local exclusive prefix
  if (t == 0) {
    __hip_atomic_store(&bsum[blockIdx.x], total, __ATOMIC_RELEASE, __HIP_MEMORY_SCOPE_AGENT);
    int tk = __hip_atomic_fetch_add(&ctl[0], 1, __ATOMIC_ACQ_REL, __HIP_MEMORY_SCOPE_AGENT);
    lastS = (tk == nb - 1);
  }
  __syncthreads();
  if (lastS) {
    if (t < 64) {
      int bv = (t < nb) ? __hip_atomic_load(&bsum[t], __ATOMIC_ACQUIRE, __HIP_MEMORY_SCOPE_AGENT) : 0;
      int a2 = bv;
#pragma unroll
      for (int off = 1; off < 64; off <<= 1) {
        int u = __shfl_up(a2, off);
        if (t >= off) a2 += u;
      }
      if (t < nb)
        __hip_atomic_store(&bases[t], a2 - bv, __ATOMIC_RELAXED, __HIP_MEMORY_SCOPE_AGENT);
    }
    __syncthreads();
    if (t == 0) {
      __threadfence();
      __hip_atomic_store(&ctl[1], 1, __ATOMIC_RELEASE, __HIP_MEMORY_SCOPE_AGENT);
    }
  }
  if (t == 0) {
    while (__hip_atomic_load(&ctl[1], __ATOMIC_ACQUIRE, __HIP_MEMORY_SCOPE_AGENT) == 0) {}
    sbase = __hip_atomic_load(&bases[blockIdx.x], __ATOMIC_RELAXED, __HIP_MEMORY_SCOPE_AGENT);
  }
  __syncthreads();
  if (i < n) A[i] = local + sbase;
}

// -------- CSR fill: A becomes row-end (inclusive) --------
__global__ __launch_bounds__(256) void k_fill(const int* __restrict__ srcT,
                                              const int* __restrict__ dst,
                                              int* __restrict__ A, int* __restrict__ adj, int E) {
  int e = blockIdx.x * 256 + threadIdx.x;
  if (e >= E) return;
  int s = srcT[e], d = dst[e];
  int slot = atomicAdd(&A[d], 1);
  adj[slot] = s;
}

// -------- mean aggregation v3: TWO dst rows per wave. DO NOT fuse into gemm (R10). --------
__global__ __launch_bounds__(256) void k_gather(const unsigned short* __restrict__ xin,
                                                const int* __restrict__ A,
                                                const int* __restrict__ adj,
                                                unsigned short* __restrict__ aggb, int N) {
  int base = blockIdx.x * 8 + ((threadIdx.x >> 6) << 1);
  int l = threadIdx.x & 63;
  int grp = l >> 4, ln = l & 15;
  const uint4* xrows = (const uint4*)xin;

  int d0 = base, d1 = base + 1;
  bool v0 = d0 < N, v1 = d1 < N;
  int e00 = 0, e01 = 0, e10 = 0, e11 = 0;
  if (v0) { e00 = (d0 == 0) ? 0 : A[d0 - 1]; e01 = A[d0]; }
  if (v1) { e10 = A[d1 - 1]; e11 = A[d1]; }  // d1 >= 1 always
  int deg0 = e01 - e00, deg1 = e11 - e10;
  int ids0 = 0, ids1 = 0;
  if (v0 && deg0 > 0) ids0 = adj[min(e00 + l, e01 - 1)];
  if (v1 && deg1 > 0) ids1 = adj[min(e10 + l, e11 - 1)];
  int m0 = (v0 && deg0 > 0) ? min(deg0, 64) : 0;
  int m1 = (v1 && deg1 > 0) ? min(deg1, 64) : 0;
  int mm = max(m0, m1);

  float acc0[8] = {0.f, 0.f, 0.f, 0.f, 0.f, 0.f, 0.f, 0.f};
  float acc1[8] = {0.f, 0.f, 0.f, 0.f, 0.f, 0.f, 0.f, 0.f};
  for (int j0 = 0; j0 < mm; j0 += 4) {
    int jj = j0 + grp;
    int s0 = __shfl(ids0, jj);
    int s1 = __shfl(ids1, jj);
    if (jj < m0) { uint4 u = xrows[(size_t)s0 * 16 + ln]; add8(acc0, u); }
    if (jj < m1) { uint4 u = xrows[(size_t)s1 * 16 + ln]; add8(acc1, u); }
  }
  for (int e = e00 + 64 + grp; e < e01; e += 4) {  // rare: deg > 64
    int s = adj[e];
    uint4 u = xrows[(size_t)s * 16 + ln];
    add8(acc0, u);
  }
  for (int e = e10 + 64 + grp; e < e11; e += 4) {
    int s = adj[e];
    uint4 u = xrows[(size_t)s * 16 + ln];
    add8(acc1, u);
  }
#pragma unroll
  for (int k2 = 0; k2 < 8; ++k2) {
    acc0[k2] += __shfl_xor(acc0[k2], 16);
    acc0[k2] += __shfl_xor(acc0[k2], 32);
    acc1[k2] += __shfl_xor(acc1[k2], 16);
    acc1[k2] += __shfl_xor(acc1[k2], 32);
  }
  if (grp == 0) {
    if (v0) {
      float inv = 1.0f / fmaxf((float)deg0, 1.0f);
      uint4 o = make_uint4(pack2(acc0[0] * inv, acc0[1] * inv), pack2(acc0[2] * inv, acc0[3] * inv),
                           pack2(acc0[4] * inv, acc0[5] * inv), pack2(acc0[6] * inv, acc0[7] * inv));
      ((uint4*)aggb)[(size_t)d0 * 16 + ln] = o;
    }
    if (v1) {
      float inv = 1.0f / fmaxf((float)deg1, 1.0f);
      uint4 o = make_uint4(pack2(acc1[0] * inv, acc1[1] * inv), pack2(acc1[2] * inv, acc1[3] * inv),
                           pack2(acc1[4] * inv, acc1[5] * inv), pack2(acc1[6] * inv, acc1[7] * inv));
      ((uint4*)aggb)[(size_t)d1 * 16 + ln] = o;
    }
  }
}

// -------- MFMA gemm: hb[N][128] = bf16([aggb | xb] @ Wcat + bias); BN partials to pbuf --------
// R11-exact. Epilogue = plain stores only. R12 folded the ticketed finalize in
// here and the allocator dropped to 48 VGPRs, spilling bfrag -> 300 us (R4's
// disease). Keep ALL cross-block coordination OUT of this kernel.
__global__ __launch_bounds__(256, 2) void k_gemm(
    const unsigned short* __restrict__ aggb, const unsigned short* __restrict__ xb,
    const unsigned short* __restrict__ WcatT, const float* __restrict__ bias,
    unsigned short* __restrict__ hb, float* __restrict__ pbuf, int N) {
  const int w = threadIdx.x >> 6;
  const int l = threadIdx.x & 63;
  const int lm = l & 15;   // tile row (A) / tile col (B, C/D)
  const int lq = l >> 4;   // quad
  const int cbase = 32 * w;

  short8 bfrag[2][8];
#pragma unroll
  for (int c = 0; c < 2; ++c) {
    int col = cbase + 16 * c + lm;
    const unsigned short* wp = WcatT + (size_t)col * 256 + lq * 8;
#pragma unroll
    for (int s = 0; s < 8; ++s) bfrag[c][s] = *(const short8*)(wp + 32 * s);
  }
  float bcol0 = bias[cbase + lm];
  float bcol1 = bias[cbase + 16 + lm];
  float bsum0 = 0.f, bsum1 = 0.f, bsq0 = 0.f, bsq1 = 0.f;

  int r0 = blockIdx.x * 64;  // grid == nRowBlocks
  floatx4 acc[4][2] = {};
#pragma unroll
  for (int t = 0; t < 4; ++t) {
    int r = r0 + 16 * t + lm;  // pad rows exist (poison = tiny bf16); stores/stats guarded
    const unsigned short* arow = aggb + (size_t)r * F + lq * 8;
    const unsigned short* xrow = xb + (size_t)r * F + lq * 8;
    short8 af[8];
#pragma unroll
    for (int s = 0; s < 4; ++s) {
      af[s] = *(const short8*)(arow + 32 * s);
      af[s + 4] = *(const short8*)(xrow + 32 * s);
    }
#pragma unroll
    for (int s = 0; s < 8; ++s) {
      acc[t][0] = __builtin_amdgcn_mfma_f32_16x16x32_bf16(af[s], bfrag[0][s], acc[t][0], 0, 0, 0);
      acc[t][1] = __builtin_amdgcn_mfma_f32_16x16x32_bf16(af[s], bfrag[1][s], acc[t][1], 0, 0, 0);
    }
  }
#pragma unroll
  for (int t = 0; t < 4; ++t) {
#pragma unroll
    for (int c = 0; c < 2; ++c) {
      int col = cbase + 16 * c + lm;
      float bc = c ? bcol1 : bcol0;
#pragma unroll
      for (int g = 0; g < 4; ++g) {
        int row = r0 + 16 * t + lq * 4 + g;
        if (row < N) {
          float v = acc[t][c][g] + bc;
          hb[(size_t)row * F + col] = f2bf(v);
          if (c) { bsum1 += v; bsq1 += v * v; }
          else   { bsum0 += v; bsq0 += v * v; }
        }
      }
    }
  }
  bsum0 += __shfl_xor(bsum0, 16); bsum0 += __shfl_xor(bsum0, 32);
  bsq0  += __shfl_xor(bsq0, 16);  bsq0  += __shfl_xor(bsq0, 32);
  bsum1 += __shfl_xor(bsum1, 16); bsum1 += __shfl_xor(bsum1, 32);
  bsq1  += __shfl_xor(bsq1, 16);  bsq1  += __shfl_xor(bsq1, 32);
  if (lq == 0) {
    float* pb = pbuf + (size_t)blockIdx.x * 256;
    pb[cbase + lm]            = bsum0;
    pb[128 + cbase + lm]      = bsq0;
    pb[cbase + 16 + lm]       = bsum1;
    pb[128 + cbase + 16 + lm] = bsq1;
  }
}

// -------- BN stats: grid-8 reduce of pbuf + ticketed last-block finalize --------
__global__ __launch_bounds__(256) void k_bnstats(const float* __restrict__ pbuf,
                                                 const float* __restrict__ g,
                                                 const float* __restrict__ be,
                                                 float* __restrict__ stats,
                                                 float* __restrict__ scale,
                                                 float* __restrict__ shift,
                                                 float invN, int nb) {
  int t = threadIdx.x;
  float s = 0.f;
  for (int b = blockIdx.x; b < nb; b += 8) s += pbuf[(size_t)b * 256 + t];
  atomicAdd(&stats[t], s);
  __threadfence();
  __syncthreads();
  __shared__ int lastS;
  if (t == 0) {
    int ticket = atomicAdd((int*)(stats + 256), 1);
    lastS = (ticket == 7);
  }
  __syncthreads();
  if (lastS) {
    __threadfence();
    if (t < 128) {
      float sum = __hip_atomic_load(&stats[t], __ATOMIC_RELAXED, __HIP_MEMORY_SCOPE_AGENT);
      float sq  = __hip_atomic_load(&stats[t + 128], __ATOMIC_RELAXED, __HIP_MEMORY_SCOPE_AGENT);
      float mu = sum * invN;
      float var = fmaxf(sq * invN - mu * mu, 0.0f);
      float sc = g[t] * rsqrtf(var + 1e-5f);
      scale[t] = sc;
      shift[t] = be[t] - mu * sc;
    }
  }
}

// -------- BN apply + ReLU: bf16 h -> bf16 dst (8 elems/thread) --------
__global__ __launch_bounds__(256) void k_bnrelu(const unsigned short* __restrict__ h,
                                                unsigned short* __restrict__ dst,
                                                const float* __restrict__ scale,
                                                const float* __restrict__ shift, int n8) {
  int i = blockIdx.x * 256 + threadIdx.x;
  if (i >= n8) return;
  uint4 u = ((const uint4*)h)[i];
  int g = i & 15;
  float4 sc0 = ((const float4*)scale)[2 * g];
  float4 sc1 = ((const float4*)scale)[2 * g + 1];
  float4 sh0 = ((const float4*)shift)[2 * g];
  float4 sh1 = ((const float4*)shift)[2 * g + 1];
  unsigned o0 = pack2(fmaxf(fmaf(bf_lo(u.x), sc0.x, sh0.x), 0.f),
                      fmaxf(fmaf(bf_hi(u.x), sc0.y, sh0.y), 0.f));
  unsigned o1 = pack2(fmaxf(fmaf(bf_lo(u.y), sc0.z, sh0.z), 0.f),
                      fmaxf(fmaf(bf_hi(u.y), sc0.w, sh0.w), 0.f));
  unsigned o2 = pack2(fmaxf(fmaf(bf_lo(u.z), sc1.x, sh1.x), 0.f),
                      fmaxf(fmaf(bf_hi(u.z), sc1.y, sh1.y), 0.f));
  unsigned o3 = pack2(fmaxf(fmaf(bf_lo(u.w), sc1.z, sh1.z), 0.f),
                      fmaxf(fmaf(bf_hi(u.w), sc1.w, sh1.w), 0.f));
  ((uint4*)dst)[i] = make_uint4(o0, o1, o2, o3);
}

// -------- fused BN1 + ReLU + final linear 128->2: hb -> out --------
__global__ __launch_bounds__(256) void k_bnout(const unsigned short* __restrict__ hb,
                                               const float* __restrict__ scale,
                                               const float* __restrict__ shift,
                                               const float* __restrict__ Wout,
                                               const float* __restrict__ bout,
                                               float* __restrict__ out, int N) {
  __shared__ float W0s[F], W1s[F];
  int t = threadIdx.x;
  if (t < F) {
    W0s[t] = Wout[2 * t];
    W1s[t] = Wout[2 * t + 1];
  }
  __syncthreads();
  int r = blockIdx.x * 16 + (t >> 4);
  int ln = t & 15;
  if (r >= N) return;
  uint4 u = ((const uint4*)(hb + (size_t)r * F))[ln];
  float4 sc0 = ((const float4*)scale)[2 * ln];
  float4 sc1 = ((const float4*)scale)[2 * ln + 1];
  float4 sh0 = ((const float4*)shift)[2 * ln];
  float4 sh1 = ((const float4*)shift)[2 * ln + 1];
  float v[8];
  v[0] = fmaxf(fmaf(bf_lo(u.x), sc0.x, sh0.x), 0.f);
  v[1] = fmaxf(fmaf(bf_hi(u.x), sc0.y, sh0.y), 0.f);
  v[2] = fmaxf(fmaf(bf_lo(u.y), sc0.z, sh0.z), 0.f);
  v[3] = fmaxf(fmaf(bf_hi(u.y), sc0.w, sh0.w), 0.f);
  v[4] = fmaxf(fmaf(bf_lo(u.z), sc1.x, sh1.x), 0.f);
  v[5] = fmaxf(fmaf(bf_hi(u.z), sc1.y, sh1.y), 0.f);
  v[6] = fmaxf(fmaf(bf_lo(u.w), sc1.z, sh1.z), 0.f);
  v[7] = fmaxf(fmaf(bf_hi(u.w), sc1.w, sh1.w), 0.f);
  float a0 = 0.f, a1 = 0.f;
#pragma unroll
  for (int j = 0; j < 8; ++j) {
    a0 += v[j] * W0s[8 * ln + j];
    a1 += v[j] * W1s[8 * ln + j];
  }
#pragma unroll
  for (int off = 1; off < 16; off <<= 1) {
    a0 += __shfl_xor(a0, off);
    a1 += __shfl_xor(a1, off);
  }
  if (ln == 0) {
    out[2 * r]     = a0 + bout[0];
    out[2 * r + 1] = a1 + bout[1];
  }
}

extern "C" void kernel_launch(void* const* d_in, const int* in_sizes, int n_in,
                              void* d_out, int out_size, void* d_ws, size_t ws_size,
                              hipStream_t stream) {
  const float* x   = (const float*)d_in[0];
  const int*   eix = (const int*)d_in[1];
  const float* Wl0 = (const float*)d_in[2];
  const float* Wr0 = (const float*)d_in[3];
  const float* b0  = (const float*)d_in[4];
  const float* g0  = (const float*)d_in[5];
  const float* be0 = (const float*)d_in[6];
  const float* Wl1 = (const float*)d_in[7];
  const float* Wr1 = (const float*)d_in[8];
  const float* b1  = (const float*)d_in[9];
  const float* g1  = (const float*)d_in[10];
  const float* be1 = (const float*)d_in[11];
  const float* Wo  = (const float*)d_in[12];
  const float* bo  = (const float*)d_in[13];

  int N = in_sizes[0] / F;     // 50000
  int E = in_sizes[1] / 2;     // 600000
  const int* src  = eix;
  const int* dstv = eix + E;

  int nRowBlocks = (N + 63) / 64;         // 782
  size_t Npad = (size_t)nRowBlocks * 64;  // 50048
  int nScanB = (N + 1023) / 1024;         // 49

  // ws layout: aggb | xb | hb (bf16 Npad*F) | WcatT0 | WcatT1 | scale | shift |
  //            A[N] | bsum[64] | bases[64] | ctl[4] | stats0[257] | stats1[257] | adj[E] | pbuf
  unsigned short* aggb   = (unsigned short*)d_ws;
  unsigned short* xb     = aggb + Npad * F;
  unsigned short* hb     = xb + Npad * F;
  unsigned short* WcatT0 = hb + Npad * F;
  unsigned short* WcatT1 = WcatT0 + 256 * F;
  float* scale  = (float*)(WcatT1 + 256 * F);
  float* shift  = scale + F;
  int*   A      = (int*)(shift + F);
  int*   bsum   = A + N;
  int*   bases  = bsum + 64;
  int*   ctl    = bases + 64;            // [0]=scan ticket [1]=scan release flag
  float* stats0 = (float*)(ctl + 4);     // 256 f + 1 int ticket
  float* stats1 = stats0 + 257;
  int*   adj    = (int*)(stats1 + 257);
  float* pbuf   = (float*)(adj + E);     // [nRowBlocks][256]

  // zero A + bsum + bases + ctl + stats0/1 in one contiguous memset
  hipMemsetAsync(A, 0, (size_t)(N + 132 + 514) * sizeof(int), stream);

  int n4 = N * F / 4, n8 = N * F / 8;
  int cb = (E + 255) / 256;

  // ---- merged: histogram + x conversion + weight transposes ----
  k_pre<<<cb + (n4 + 2 * 256 * F + 255) / 256, 256, 0, stream>>>(
      dstv, A, E, cb, x, Wl0, Wr0, Wl1, Wr1, xb, WcatT0, WcatT1, n4);

  // ---- CSR scan (single kernel) + fill ----
  k_scan<<<nScanB, 1024, 0, stream>>>(A, bsum, bases, ctl, N, nScanB);
  k_fill<<<(E + 255) / 256, 256, 0, stream>>>(src, dstv, A, adj, E);

  // ---- layer 0 ----
  k_gather<<<(N + 7) / 8, 256, 0, stream>>>(xb, A, adj, aggb, N);
  k_gemm<<<nRowBlocks, 256, 0, stream>>>(aggb, xb, WcatT0, b0, hb, pbuf, N);
  k_bnstats<<<8, 256, 0, stream>>>(pbuf, g0, be0, stats0, scale, shift, 1.0f / N, nRowBlocks);
  k_bnrelu<<<(n8 + 255) / 256, 256, 0, stream>>>(hb, xb, scale, shift, n8);  // -> xb

  // ---- layer 1 ----
  k_gather<<<(N + 7) / 8, 256, 0, stream>>>(xb, A, adj, aggb, N);
  k_gemm<<<nRowBlocks, 256, 0, stream>>>(aggb, xb, WcatT1, b1, hb, pbuf, N);
  k_bnstats<<<8, 256, 0, stream>>>(pbuf, g1, be1, stats1, scale, shift, 1.0f / N, nRowBlocks);

  // ---- fused BN1 + ReLU + output head ----
  k_bnout<<<(N + 15) / 16, 256, 0, stream>>>(hb, scale, shift, Wo, bo, (float*)d_out, N);
}